// Round 8
// baseline (144.713 us; speedup 1.0000x reference)
//
#include <hip/hip_runtime.h>
#include <math.h>

// Deepmd angular descriptor, f32 in / f32 out. B=8, N=4096, M=96, OUT_W=384.
//
// R8 vs R7 (52 us total; latency-bound, VALU<30%, HBM<25%): barrier-free
// persistent pipeline.
//  - One PAIR per WAVE: lane handles m=lane, and m=64+(lane&31) for lanes<32.
//    cut_s / out_s are per-wave LDS slices -> NO __syncthreads anywhere ->
//    no s_waitcnt vmcnt(0) drains; same-wave DS ops execute in order.
//  - 2048 blocks x 256 thr = 8 blocks/CU fully resident (launch_bounds(256,8),
//    VGPR<=64). Each wave runs NITER=4 pairs, inputs prefetched 2 pairs ahead,
//    gathers 1 pair ahead -> ~15 outstanding loads/lane (vs ~6 before).
//  - Output rows emitted from LDS (zeros + rare scatters fused) -> no separate
//    fill kernel. pos_i / cell via readfirstlane -> scalar loads.
#define M_NB  96
#define OUT_W 384
#define WPB   4      // waves per block
#define NITER 4      // pairs per wave; pairs/block = WPB*NITER = 16

struct Items {       // per-lane pipeline bundle: 2 neighbor items (A, B)
    int   jA, jB;
    float mkA, mkB;
    float oA0, oA1, oA2, oB0, oB1, oB2;
};

__device__ __forceinline__ void load_items(Items& it_,
    const int* __restrict__ nb, const float* __restrict__ mk,
    const float* __restrict__ of, long q, int mA, int mB)
{
    const long eA = q * M_NB + mA, eB = q * M_NB + mB;
    it_.jA  = nb[eA];       it_.jB  = nb[eB];
    it_.mkA = mk[eA];       it_.mkB = mk[eB];
    it_.oA0 = of[eA * 3];   it_.oA1 = of[eA * 3 + 1]; it_.oA2 = of[eA * 3 + 2];
    it_.oB0 = of[eB * 3];   it_.oB1 = of[eB * 3 + 1]; it_.oB2 = of[eB * 3 + 2];
}

struct Gath { float ax, ay, az, bx, by, bz; };

__device__ __forceinline__ void load_gath(Gath& g,
    const float* __restrict__ pos, long posb, int jA, int jB)
{
    const float* pa = pos + posb + (long)jA * 3;
    const float* pb = pos + posb + (long)jB * 3;
    g.ax = pa[0]; g.ay = pa[1]; g.az = pa[2];
    g.bx = pb[0]; g.by = pb[1]; g.bz = pb[2];
}

__global__ __launch_bounds__(64 * WPB, 8) void deepmd_angular_kernel(
    const float* __restrict__ positions,  // [B,N,3]
    const float* __restrict__ cell,       // [B,3,3]
    const float* __restrict__ offsets,    // [B,N,M,3]
    const float* __restrict__ mask,       // [B,N,M]
    const int*   __restrict__ neighbors,  // [B,N,M]
    float*       __restrict__ out,        // [B,N,OUT_W]
    int N)
{
    __shared__ float cut_s[WPB][M_NB];    // per-wave slice
    __shared__ float out_s[WPB][OUT_W];   // per-wave full row (incl. zero pad)

    const int tid  = threadIdx.x;
    const int wv   = tid >> 6;
    const int lane = tid & 63;
    const int l32  = lane & 31;
    const bool low = lane < 32;
    const int mA   = lane;
    const int mB   = 64 + l32;            // valid item only when low

    const int qbase = blockIdx.x * (WPB * NITER) + wv;   // pair: qbase + WPB*it
    const int b     = __builtin_amdgcn_readfirstlane(qbase) / N; // uniform (16|N)

    // cell: uniform per block -> scalar loads
    const float* cb = cell + (size_t)b * 9;
    const float c00 = cb[0], c01 = cb[1], c02 = cb[2];
    const float c10 = cb[3], c11 = cb[4], c12 = cb[5];
    const float c20 = cb[6], c21 = cb[7], c22 = cb[8];
    const long posb = (long)b * N * 3;

    // ---- pipeline prologue ----
    Items cur, nxt;
    Gath  gc, gn;
    load_items(cur, neighbors, mask, offsets, qbase, mA, mB);
    load_gath(gc, positions, posb, cur.jA, cur.jB);
    load_items(nxt, neighbors, mask, offsets, qbase + WPB, mA, mB);

    const float4 z4 = make_float4(0.f, 0.f, 0.f, 0.f);

    #pragma unroll
    for (int it = 0; it < NITER; ++it) {
        const long q  = qbase + (long)WPB * it;
        const int  uq = __builtin_amdgcn_readfirstlane((int)q);

        // prefetch: inputs two pairs ahead (independent -> issue first)
        Items nxt2;
        if (it + 2 < NITER)
            load_items(nxt2, neighbors, mask, offsets, qbase + (long)WPB * (it + 2), mA, mB);
        // prefetch: gather one pair ahead (depends on nxt.j)
        if (it + 1 < NITER)
            load_gath(gn, positions, posb, nxt.jA, nxt.jB);

        // pos_i: wave-uniform -> scalar loads
        const float* pu = positions + (size_t)uq * 3;
        const float pix = pu[0], piy = pu[1], piz = pu[2];

        // ---- compute both items ----
        const float dxA = gc.ax - pix + cur.oA0 * c00 + cur.oA1 * c10 + cur.oA2 * c20;
        const float dyA = gc.ay - piy + cur.oA0 * c01 + cur.oA1 * c11 + cur.oA2 * c21;
        const float dzA = gc.az - piz + cur.oA0 * c02 + cur.oA1 * c12 + cur.oA2 * c22;
        const float dxB = gc.bx - pix + cur.oB0 * c00 + cur.oB1 * c10 + cur.oB2 * c20;
        const float dyB = gc.by - piy + cur.oB0 * c01 + cur.oB1 * c11 + cur.oB2 * c21;
        const float dzB = gc.bz - piz + cur.oB0 * c02 + cur.oB1 * c12 + cur.oB2 * c22;

        const float dA = sqrtf(dxA * dxA + dyA * dyA + dzA * dzA + 1e-12f);
        const float dB = sqrtf(dxB * dxB + dyB * dyB + dzB * dzB + 1e-12f);

        float cutA = 0.f, cutB = 0.f;
        if (cur.mkA != 0.f && dA < 6.f)
            cutA = 0.5f * (cosf(dA * 0.52359877559829887f) + 1.f) / dA;
        if (cur.mkB != 0.f && dB < 6.f)
            cutB = 0.5f * (cosf(dB * 0.52359877559829887f) + 1.f) / dB;

        // ---- wave-local LDS phase (no barriers; same-wave DS is in-order) ----
        float4* os4 = (float4*)out_s[wv];
        os4[lane] = z4;                       // floats 0..255
        if (low) os4[64 + l32] = z4;          // floats 256..383
        cut_s[wv][mA] = cutA;
        if (low) cut_s[wv][mB] = cutB;

        // rare path: stable descending rank + LDS scatter (~0.45% of items)
        // rank(m) = #{k: cut_k > cut_m} + #{k<m: cut_k == cut_m}
        if (cutA != 0.f) {
            int rank = 0;
            const float4* c4 = (const float4*)cut_s[wv];
            #pragma unroll
            for (int k4 = 0; k4 < M_NB / 4; ++k4) {
                const float4 c = c4[k4];
                const int k = 4 * k4;
                rank += (c.x > cutA) || (c.x == cutA && k + 0 < mA);
                rank += (c.y > cutA) || (c.y == cutA && k + 1 < mA);
                rank += (c.z > cutA) || (c.z == cutA && k + 2 < mA);
                rank += (c.w > cutA) || (c.w == cutA && k + 3 < mA);
            }
            out_s[wv][rank * 3 + 0] = cutA * dxA;
            out_s[wv][rank * 3 + 1] = cutA * dyA;
            out_s[wv][rank * 3 + 2] = cutA * dzA;
        }
        if (low && cutB != 0.f) {
            int rank = 0;
            const float4* c4 = (const float4*)cut_s[wv];
            #pragma unroll
            for (int k4 = 0; k4 < M_NB / 4; ++k4) {
                const float4 c = c4[k4];
                const int k = 4 * k4;
                rank += (c.x > cutB) || (c.x == cutB && k + 0 < mB);
                rank += (c.y > cutB) || (c.y == cutB && k + 1 < mB);
                rank += (c.z > cutB) || (c.z == cutB && k + 2 < mB);
                rank += (c.w > cutB) || (c.w == cutB && k + 3 < mB);
            }
            out_s[wv][rank * 3 + 0] = cutB * dxB;
            out_s[wv][rank * 3 + 1] = cutB * dyB;
            out_s[wv][rank * 3 + 2] = cutB * dzB;
        }

        // ---- emit full row (coalesced float4) ----
        float4* orow = (float4*)(out + (size_t)q * OUT_W);
        orow[lane] = os4[lane];
        if (low) orow[64 + l32] = os4[64 + l32];

        // ---- rotate pipeline ----
        cur = nxt; gc = gn; nxt = nxt2;
    }
}

extern "C" void kernel_launch(void* const* d_in, const int* in_sizes, int n_in,
                              void* d_out, int out_size, void* d_ws, size_t ws_size,
                              hipStream_t stream) {
    const float* positions = (const float*)d_in[0];
    const float* cell      = (const float*)d_in[1];
    const float* offsets   = (const float*)d_in[2];
    const float* mask      = (const float*)d_in[3];
    const int*   neighbors = (const int*)d_in[4];
    float*       out       = (float*)d_out;

    const int BN = in_sizes[0] / 3;        // B*N = 32768
    const int B  = in_sizes[1] / 9;        // 8
    const int N  = BN / B;                 // 4096

    dim3 block(64 * WPB, 1, 1);            // 256 threads
    dim3 grid(BN / (WPB * NITER), 1, 1);   // 2048 blocks = 8/CU resident
    deepmd_angular_kernel<<<grid, block, 0, stream>>>(
        positions, cell, offsets, mask, neighbors, out, N);
}

// Round 9
// 123.003 us; speedup vs baseline: 1.1765x; 1.1765x over previous
//
#include <hip/hip_runtime.h>
#include <math.h>

// Deepmd angular descriptor, f32 in / f32 out. B=8, N=4096, M=96, OUT_W=384.
//
// R9 theory: R4-R8 all plateau at 42-55 us with VALU<=30% and HBM<=25% --
// the shared cost is the per-lane random gather positions[j] (3 dwords, 64
// distinct lines per wave-op, L1-missing: 48 KB table > 32 KB L1 + stream
// pollution). Fix: stage the batch's whole position table in LDS once per
// block; gathers become ds_read_b32. Also: full-wave row-zero stores (R8's
// half-wave 512 B tails inflated WRITE_SIZE 7/6), issued first each
// iteration so the mandatory 49 MB write stream overlaps everything.
//   block = 1024 thr = 16 waves; 64 pairs/block (batch-uniform); grid = 512
//   = 2 blocks/CU resident; LDS = 48 KB positions + 6 KB cut = 54 KB.
#define M_NB   96
#define OUT_W  384
#define NATOM  4096        // N (fixed problem shape)
#define WPB    16          // waves per block
#define NITER  4           // pairs per wave; pairs/block = 64

__global__ __launch_bounds__(64 * WPB, 8) void deepmd_angular_kernel(
    const float* __restrict__ positions,  // [B,N,3]
    const float* __restrict__ cell,       // [B,3,3]
    const float* __restrict__ offsets,    // [B,N,M,3]
    const float* __restrict__ mask,       // [B,N,M]
    const int*   __restrict__ neighbors,  // [B,N,M]
    float*       __restrict__ out,        // [B,N,OUT_W]
    int N)
{
    __shared__ float pos_s[NATOM * 3];      // 48 KB: batch position table
    __shared__ float cut_s[WPB][M_NB];      // 6 KB: per-wave cut exchange

    const int tid  = threadIdx.x;
    const int wv   = tid >> 6;
    const int lane = tid & 63;
    const bool low = lane < 32;

    const int p0 = blockIdx.x * (WPB * NITER);   // first pair of block
    const int b  = p0 / N;                       // uniform (64 | N)

    // ---- stage batch positions global -> LDS (coalesced float4 copy) ----
    {
        const float4* src = (const float4*)(positions + (size_t)b * N * 3);
        float4* dst = (float4*)pos_s;
        const int nf4 = (N * 3) >> 2;            // 3072
        #pragma unroll
        for (int i = tid; i < nf4; i += 64 * WPB) dst[i] = src[i];
    }
    __syncthreads();                             // only barrier in the kernel

    // cell: uniform per block -> scalar loads
    const float* cb = cell + (size_t)b * 9;
    const float c00 = cb[0], c01 = cb[1], c02 = cb[2];
    const float c10 = cb[3], c11 = cb[4], c12 = cb[5];
    const float c20 = cb[6], c21 = cb[7], c22 = cb[8];

    const float4 z4 = make_float4(0.f, 0.f, 0.f, 0.f);
    const float2 z2 = make_float2(0.f, 0.f);

    #pragma unroll
    for (int it = 0; it < NITER; ++it) {
        const int q  = p0 + wv * NITER + it;     // this wave's pair
        const int nn = q - b * N;                // local atom index

        // ---- zero this pair's output row FIRST (full-wave stores) ----
        // 384 floats = 64 x float4 (0..255) + 64 x float2 (256..383)
        float* rowp = out + (size_t)q * OUT_W;
        ((float4*)rowp)[lane] = z4;
        ((float2*)(rowp + 256))[lane] = z2;

        // ---- per-neighbor inputs: item A (m=lane), item B (m=64+lane, lane<32) ----
        const long eA = (long)q * M_NB + lane;
        const int   jA  = neighbors[eA];
        const float mkA = mask[eA];
        const float oA0 = offsets[eA * 3], oA1 = offsets[eA * 3 + 1], oA2 = offsets[eA * 3 + 2];

        int jB = 0; float mkB = 0.f, oB0 = 0.f, oB1 = 0.f, oB2 = 0.f;
        if (low) {
            const long eB = eA + 64;
            jB  = neighbors[eB];
            mkB = mask[eB];
            oB0 = offsets[eB * 3]; oB1 = offsets[eB * 3 + 1]; oB2 = offsets[eB * 3 + 2];
        }

        // pos_i: wave-uniform LDS broadcast
        const float pix = pos_s[nn * 3 + 0];
        const float piy = pos_s[nn * 3 + 1];
        const float piz = pos_s[nn * 3 + 2];

        // ---- gathers from LDS (3 x ds_read_b32, random bank) ----
        const float axA = pos_s[jA * 3 + 0], ayA = pos_s[jA * 3 + 1], azA = pos_s[jA * 3 + 2];

        const float dxA = axA - pix + oA0 * c00 + oA1 * c10 + oA2 * c20;
        const float dyA = ayA - piy + oA0 * c01 + oA1 * c11 + oA2 * c21;
        const float dzA = azA - piz + oA0 * c02 + oA1 * c12 + oA2 * c22;
        const float dA  = sqrtf(dxA * dxA + dyA * dyA + dzA * dzA + 1e-12f);
        float cutA = 0.f;
        if (mkA != 0.f && dA < 6.f)
            cutA = 0.5f * (cosf(dA * 0.52359877559829887f) + 1.f) / dA;

        float dxB = 0.f, dyB = 0.f, dzB = 0.f, cutB = 0.f;
        if (low) {
            const float axB = pos_s[jB * 3 + 0], ayB = pos_s[jB * 3 + 1], azB = pos_s[jB * 3 + 2];
            dxB = axB - pix + oB0 * c00 + oB1 * c10 + oB2 * c20;
            dyB = ayB - piy + oB0 * c01 + oB1 * c11 + oB2 * c21;
            dzB = azB - piz + oB0 * c02 + oB1 * c12 + oB2 * c22;
            const float dB = sqrtf(dxB * dxB + dyB * dyB + dzB * dzB + 1e-12f);
            if (mkB != 0.f && dB < 6.f)
                cutB = 0.5f * (cosf(dB * 0.52359877559829887f) + 1.f) / dB;
        }

        // ---- wave-local cut exchange (same-wave DS ordering, no barrier) ----
        cut_s[wv][lane] = cutA;
        if (low) cut_s[wv][64 + lane] = cutB;

        // ---- rare path (~0.45% of items): stable rank + 12 B global scatter ----
        // rank(m) = #{k: cut_k > cut_m} + #{k<m: cut_k == cut_m}; zero-cut
        // items sort after all nonzero ones and contribute exact zeros.
        if (cutA != 0.f || cutB != 0.f) {
            __threadfence_block();               // drain row-zero stores (vmcnt)
            if (cutA != 0.f) {
                const int mA = lane;
                int rank = 0;
                const float4* c4 = (const float4*)cut_s[wv];
                #pragma unroll
                for (int k4 = 0; k4 < M_NB / 4; ++k4) {
                    const float4 c = c4[k4];     // ds_read_b128 broadcast
                    const int k = 4 * k4;
                    rank += (c.x > cutA) || (c.x == cutA && k + 0 < mA);
                    rank += (c.y > cutA) || (c.y == cutA && k + 1 < mA);
                    rank += (c.z > cutA) || (c.z == cutA && k + 2 < mA);
                    rank += (c.w > cutA) || (c.w == cutA && k + 3 < mA);
                }
                rowp[rank * 3 + 0] = cutA * dxA;
                rowp[rank * 3 + 1] = cutA * dyA;
                rowp[rank * 3 + 2] = cutA * dzA;
            }
            if (low && cutB != 0.f) {
                const int mB = 64 + lane;
                int rank = 0;
                const float4* c4 = (const float4*)cut_s[wv];
                #pragma unroll
                for (int k4 = 0; k4 < M_NB / 4; ++k4) {
                    const float4 c = c4[k4];
                    const int k = 4 * k4;
                    rank += (c.x > cutB) || (c.x == cutB && k + 0 < mB);
                    rank += (c.y > cutB) || (c.y == cutB && k + 1 < mB);
                    rank += (c.z > cutB) || (c.z == cutB && k + 2 < mB);
                    rank += (c.w > cutB) || (c.w == cutB && k + 3 < mB);
                }
                rowp[rank * 3 + 0] = cutB * dxB;
                rowp[rank * 3 + 1] = cutB * dyB;
                rowp[rank * 3 + 2] = cutB * dzB;
            }
        }
    }
}

extern "C" void kernel_launch(void* const* d_in, const int* in_sizes, int n_in,
                              void* d_out, int out_size, void* d_ws, size_t ws_size,
                              hipStream_t stream) {
    const float* positions = (const float*)d_in[0];
    const float* cell      = (const float*)d_in[1];
    const float* offsets   = (const float*)d_in[2];
    const float* mask      = (const float*)d_in[3];
    const int*   neighbors = (const int*)d_in[4];
    float*       out       = (float*)d_out;

    const int BN = in_sizes[0] / 3;        // B*N = 32768
    const int B  = in_sizes[1] / 9;        // 8
    const int N  = BN / B;                 // 4096

    dim3 block(64 * WPB, 1, 1);            // 1024 threads = 16 waves
    dim3 grid(BN / (WPB * NITER), 1, 1);   // 512 blocks = 2/CU resident
    deepmd_angular_kernel<<<grid, block, 0, stream>>>(
        positions, cell, offsets, mask, neighbors, out, N);
}